// Round 7
// baseline (92.856 us; speedup 1.0000x reference)
//
#include <hip/hip_runtime.h>

#define EPS 1e-7f
#define NCH 29
#define SPB 64           // samples per block (one per lane)
#define ROWF4 59         // padded float4 stride per sample in obuf (58 + 1)

// MLP sizes: 7 -> 5 -> 4 -> 4 -> 3, per-channel weights.
// W0: [c][7][5]  b0: [c][5]
// W1: [c][5][4]  b1: [c][4]
// W2: [c][4][4]  b2: [c][4]
// W3: [c][4][3]  b3: [c][3]

// Barrier ordering LDS only (lgkmcnt), not global stores (vmcnt).
__device__ __forceinline__ void barrier_lds_only() {
    asm volatile("s_waitcnt lgkmcnt(0)\n\ts_barrier" ::: "memory");
}

// Scalar MLP. Weight addresses are wave-uniform -> s_load into SGPRs;
// v_fma_f32 consumes the SGPR weight directly (1 SGPR operand allowed),
// so no per-weight v_mov materialization (unlike the packed f32x2 path).
__device__ __forceinline__ void mlp7(const float x[7],
    const float* __restrict__ W0, const float* __restrict__ b0,
    const float* __restrict__ W1, const float* __restrict__ b1,
    const float* __restrict__ W2, const float* __restrict__ b2,
    const float* __restrict__ W3, const float* __restrict__ b3,
    float e[3])
{
    float h0[5];
#pragma unroll
    for (int h = 0; h < 5; ++h) {
        float a = b0[h];
#pragma unroll
        for (int f = 0; f < 7; ++f) a = fmaf(x[f], W0[f * 5 + h], a);
        h0[h] = fmaxf(a, 0.0f);
    }
    float h1[4];
#pragma unroll
    for (int k = 0; k < 4; ++k) {
        float a = b1[k];
#pragma unroll
        for (int h = 0; h < 5; ++h) a = fmaf(h0[h], W1[h * 4 + k], a);
        h1[k] = fmaxf(a, 0.0f);
    }
    float h2[4];
#pragma unroll
    for (int k = 0; k < 4; ++k) {
        float a = b2[k];
#pragma unroll
        for (int h = 0; h < 4; ++h) a = fmaf(h1[h], W2[h * 4 + k], a);
        h2[k] = fmaxf(a, 0.0f);
    }
    float l[3];
#pragma unroll
    for (int k = 0; k < 3; ++k) {
        float a = b3[k];
#pragma unroll
        for (int h = 0; h < 4; ++h) a = fmaf(h2[h], W3[h * 3 + k], a);
        l[k] = a;
    }
    float m = fmaxf(l[0], fmaxf(l[1], l[2]));
    float e0 = __expf(l[0] - m);
    float e1 = __expf(l[1] - m);
    float e2 = __expf(l[2] - m);
    float rs = __builtin_amdgcn_rcpf(e0 + e1 + e2);
    e[0] = e0 * rs; e[1] = e1 * rs; e[2] = e2 * rs;
}

__global__ __launch_bounds__(512, 4) void lps_kernel(
    const float* __restrict__ tau, const float* __restrict__ mu, const float* __restrict__ mu_bar,
    const float* __restrict__ lw, const float* __restrict__ h2o, const float* __restrict__ o3,
    const float* __restrict__ co2, const float* __restrict__ uu, const float* __restrict__ n2o,
    const float* __restrict__ ch4,
    const float* __restrict__ Wd0, const float* __restrict__ bd0,
    const float* __restrict__ Wf0, const float* __restrict__ bf0,
    const float* __restrict__ Wd1, const float* __restrict__ bd1,
    const float* __restrict__ Wf1, const float* __restrict__ bf1,
    const float* __restrict__ Wd2, const float* __restrict__ bd2,
    const float* __restrict__ Wf2, const float* __restrict__ bf2,
    const float* __restrict__ Wd3, const float* __restrict__ bd3,
    const float* __restrict__ Wf3, const float* __restrict__ bf3,
    float* __restrict__ out, int N)
{
    __shared__ __align__(16) float4 obuf[SPB * ROWF4];  // 60416 B

    const int tid  = threadIdx.x;
    const int lane = tid & 63;
    const int wid  = __builtin_amdgcn_readfirstlane(tid >> 6);

    const long long base = (long long)blockIdx.x * SPB;
    const int s0 = (int)base + lane;
    const int i0 = (s0 < N) ? s0 : (N - 1);

    const float rmu  = __builtin_amdgcn_rcpf(mu[i0] + EPS);
    const float rmub = __builtin_amdgcn_rcpf(mu_bar[i0] + EPS);
    const float nrmu  = -rmu;
    const float nrmub = -rmub;

    float cons[7];
    cons[0] = lw[i0]; cons[1] = h2o[i0]; cons[2] = o3[i0]; cons[3] = co2[i0];
    cons[4] = uu[i0]; cons[5] = n2o[i0]; cons[6] = ch4[i0];

    float xd[7], xf[7];
#pragma unroll
    for (int f = 0; f < 7; ++f) { xd[f] = cons[f] * rmu; xf[f] = cons[f] * rmub; }

    const float* taun = tau + (size_t)i0 * NCH;

#pragma unroll
    for (int it = 0; it < 4; ++it) {
        const int c = wid + it * 8;           // wave-uniform channel
        if (c < NCH) {
            const float tv = taun[c];
            const float t_dir = __expf(tv * nrmu);
            const float t_dif = __expf(tv * nrmub);

            float ed[3], ef[3];
            mlp7(xd, Wd0 + c * 35, bd0 + c * 5, Wd1 + c * 20, bd1 + c * 4,
                     Wd2 + c * 16, bd2 + c * 4, Wd3 + c * 12, bd3 + c * 3, ed);
            mlp7(xf, Wf0 + c * 35, bf0 + c * 5, Wf1 + c * 20, bf1 + c * 4,
                     Wf2 + c * 16, bf2 + c * 4, Wf3 + c * 12, bf3 + c * 3, ef);

            obuf[lane * ROWF4 + c * 2]     = make_float4(t_dir, t_dif, ed[0], ed[1]);
            obuf[lane * ROWF4 + c * 2 + 1] = make_float4(ed[2], ef[0], ef[1], ef[2]);
        }
    }

    barrier_lds_only();

    // ---- flush: contiguous 64*928B block region, full-line coalesced ----
    float4* out4 = (float4*)out;
    int nsamp = N - (int)base;
    if (nsamp > SPB) nsamp = SPB;
    if (nsamp > 0) {
        const int tot = nsamp * 58;
        const long long ob = base * 58;
        for (int i = tid; i < tot; i += 512) {
            const int s = i / 58, r = i - s * 58;
            out4[ob + i] = obuf[s * ROWF4 + r];
        }
    }
}

extern "C" void kernel_launch(void* const* d_in, const int* in_sizes, int n_in,
                              void* d_out, int out_size, void* d_ws, size_t ws_size,
                              hipStream_t stream) {
    const float* tau    = (const float*)d_in[0];
    const float* mu     = (const float*)d_in[1];
    const float* mu_bar = (const float*)d_in[2];
    const float* lw     = (const float*)d_in[3];
    const float* h2o    = (const float*)d_in[4];
    const float* o3     = (const float*)d_in[5];
    const float* co2    = (const float*)d_in[6];
    const float* uu     = (const float*)d_in[7];
    const float* n2o    = (const float*)d_in[8];
    const float* ch4    = (const float*)d_in[9];

    const float* Wd0 = (const float*)d_in[10];
    const float* bd0 = (const float*)d_in[11];
    const float* Wf0 = (const float*)d_in[12];
    const float* bf0 = (const float*)d_in[13];
    const float* Wd1 = (const float*)d_in[14];
    const float* bd1 = (const float*)d_in[15];
    const float* Wf1 = (const float*)d_in[16];
    const float* bf1 = (const float*)d_in[17];
    const float* Wd2 = (const float*)d_in[18];
    const float* bd2 = (const float*)d_in[19];
    const float* Wf2 = (const float*)d_in[20];
    const float* bf2 = (const float*)d_in[21];
    const float* Wd3 = (const float*)d_in[22];
    const float* bd3 = (const float*)d_in[23];
    const float* Wf3 = (const float*)d_in[24];
    const float* bf3 = (const float*)d_in[25];

    float* out = (float*)d_out;
    int N = in_sizes[1];  // mu has N elements

    int blocks = (N + SPB - 1) / SPB;
    lps_kernel<<<blocks, 512, 0, stream>>>(
        tau, mu, mu_bar, lw, h2o, o3, co2, uu, n2o, ch4,
        Wd0, bd0, Wf0, bf0, Wd1, bd1, Wf1, bf1,
        Wd2, bd2, Wf2, bf2, Wd3, bd3, Wf3, bf3,
        out, N);
}

// Round 8
// 89.672 us; speedup vs baseline: 1.0355x; 1.0355x over previous
//
#include <hip/hip_runtime.h>

#define EPS 1e-7f
#define NCH 29
#define SPB 64           // samples per block (one per lane)
#define ROWA 33          // padded float4 stride per sample in obuf (32 + 1, odd -> conflict-free)

// MLP sizes: 7 -> 5 -> 4 -> 4 -> 3, per-channel weights.
// W0: [c][7][5]  b0: [c][5]
// W1: [c][5][4]  b1: [c][4]
// W2: [c][4][4]  b2: [c][4]
// W3: [c][4][3]  b3: [c][3]

// Barrier ordering LDS only (lgkmcnt), not global stores (vmcnt).
__device__ __forceinline__ void barrier_lds_only() {
    asm volatile("s_waitcnt lgkmcnt(0)\n\ts_barrier" ::: "memory");
}

// Scalar MLP: weight addresses wave-uniform -> s_load/SGPR; v_fma_f32 takes
// the SGPR weight directly (1 SGPR operand allowed), zero VGPR cost for weights.
__device__ __forceinline__ void mlp7(const float x[7],
    const float* __restrict__ W0, const float* __restrict__ b0,
    const float* __restrict__ W1, const float* __restrict__ b1,
    const float* __restrict__ W2, const float* __restrict__ b2,
    const float* __restrict__ W3, const float* __restrict__ b3,
    float e[3])
{
    float h0[5];
#pragma unroll
    for (int h = 0; h < 5; ++h) {
        float a = b0[h];
#pragma unroll
        for (int f = 0; f < 7; ++f) a = fmaf(x[f], W0[f * 5 + h], a);
        h0[h] = fmaxf(a, 0.0f);
    }
    float h1[4];
#pragma unroll
    for (int k = 0; k < 4; ++k) {
        float a = b1[k];
#pragma unroll
        for (int h = 0; h < 5; ++h) a = fmaf(h0[h], W1[h * 4 + k], a);
        h1[k] = fmaxf(a, 0.0f);
    }
    float h2[4];
#pragma unroll
    for (int k = 0; k < 4; ++k) {
        float a = b2[k];
#pragma unroll
        for (int h = 0; h < 4; ++h) a = fmaf(h1[h], W2[h * 4 + k], a);
        h2[k] = fmaxf(a, 0.0f);
    }
    float l[3];
#pragma unroll
    for (int k = 0; k < 3; ++k) {
        float a = b3[k];
#pragma unroll
        for (int h = 0; h < 4; ++h) a = fmaf(h2[h], W3[h * 3 + k], a);
        l[k] = a;
    }
    float m = fmaxf(l[0], fmaxf(l[1], l[2]));
    float e0 = __expf(l[0] - m);
    float e1 = __expf(l[1] - m);
    float e2 = __expf(l[2] - m);
    float rs = __builtin_amdgcn_rcpf(e0 + e1 + e2);
    e[0] = e0 * rs; e[1] = e1 * rs; e[2] = e2 * rs;
}

__global__ __launch_bounds__(512, 6) void lps_kernel(
    const float* __restrict__ tau, const float* __restrict__ mu, const float* __restrict__ mu_bar,
    const float* __restrict__ lw, const float* __restrict__ h2o, const float* __restrict__ o3,
    const float* __restrict__ co2, const float* __restrict__ uu, const float* __restrict__ n2o,
    const float* __restrict__ ch4,
    const float* __restrict__ Wd0, const float* __restrict__ bd0,
    const float* __restrict__ Wf0, const float* __restrict__ bf0,
    const float* __restrict__ Wd1, const float* __restrict__ bd1,
    const float* __restrict__ Wf1, const float* __restrict__ bf1,
    const float* __restrict__ Wd2, const float* __restrict__ bd2,
    const float* __restrict__ Wf2, const float* __restrict__ bf2,
    const float* __restrict__ Wd3, const float* __restrict__ bd3,
    const float* __restrict__ Wf3, const float* __restrict__ bf3,
    float* __restrict__ out, int N)
{
    __shared__ __align__(16) float4 obuf[SPB * ROWA];  // 33792 B -> LDS allows 4 blocks/CU

    const int tid  = threadIdx.x;
    const int lane = tid & 63;
    const int wid  = __builtin_amdgcn_readfirstlane(tid >> 6);

    const long long base = (long long)blockIdx.x * SPB;
    const int s0 = (int)base + lane;
    const int i0 = (s0 < N) ? s0 : (N - 1);

    const float rmu  = __builtin_amdgcn_rcpf(mu[i0] + EPS);
    const float rmub = __builtin_amdgcn_rcpf(mu_bar[i0] + EPS);
    const float nrmu  = -rmu;
    const float nrmub = -rmub;

    float cons[7];
    cons[0] = lw[i0]; cons[1] = h2o[i0]; cons[2] = o3[i0]; cons[3] = co2[i0];
    cons[4] = uu[i0]; cons[5] = n2o[i0]; cons[6] = ch4[i0];

    float xd[7], xf[7];
#pragma unroll
    for (int f = 0; f < 7; ++f) { xd[f] = cons[f] * rmu; xf[f] = cons[f] * rmub; }

    const float* taun = tau + (size_t)i0 * NCH;

    int nsamp = N - (int)base;
    if (nsamp > SPB) nsamp = SPB;
    float4* out4 = (float4*)out;

    // ================= pass A: channels 0..15 -> slots 0..31 =================
#pragma unroll
    for (int it = 0; it < 2; ++it) {
        const int c = wid + it * 8;           // wave-uniform, 0..15
        const float tv = taun[c];
        const float t_dir = __expf(tv * nrmu);
        const float t_dif = __expf(tv * nrmub);

        float ed[3], ef[3];
        mlp7(xd, Wd0 + c * 35, bd0 + c * 5, Wd1 + c * 20, bd1 + c * 4,
                 Wd2 + c * 16, bd2 + c * 4, Wd3 + c * 12, bd3 + c * 3, ed);
        mlp7(xf, Wf0 + c * 35, bf0 + c * 5, Wf1 + c * 20, bf1 + c * 4,
                 Wf2 + c * 16, bf2 + c * 4, Wf3 + c * 12, bf3 + c * 3, ef);

        obuf[lane * ROWA + c * 2]     = make_float4(t_dir, t_dif, ed[0], ed[1]);
        obuf[lane * ROWA + c * 2 + 1] = make_float4(ed[2], ef[0], ef[1], ef[2]);
    }

    barrier_lds_only();
    if (nsamp > 0) {
        const int tot = nsamp * 32;
        for (int i = tid; i < tot; i += 512) {
            const int s = i >> 5, r = i & 31;
            out4[(base + s) * 58 + r] = obuf[s * ROWA + r];
        }
    }
    barrier_lds_only();

    // ================= pass B: channels 16..28 -> slots 0..25 ================
#pragma unroll
    for (int it = 2; it < 4; ++it) {
        const int c = wid + it * 8;           // 16..31, guard at 29
        if (c < NCH) {
            const float tv = taun[c];
            const float t_dir = __expf(tv * nrmu);
            const float t_dif = __expf(tv * nrmub);

            float ed[3], ef[3];
            mlp7(xd, Wd0 + c * 35, bd0 + c * 5, Wd1 + c * 20, bd1 + c * 4,
                     Wd2 + c * 16, bd2 + c * 4, Wd3 + c * 12, bd3 + c * 3, ed);
            mlp7(xf, Wf0 + c * 35, bf0 + c * 5, Wf1 + c * 20, bf1 + c * 4,
                     Wf2 + c * 16, bf2 + c * 4, Wf3 + c * 12, bf3 + c * 3, ef);

            const int slot = (c - 16) * 2;    // 0..25
            obuf[lane * ROWA + slot]     = make_float4(t_dir, t_dif, ed[0], ed[1]);
            obuf[lane * ROWA + slot + 1] = make_float4(ed[2], ef[0], ef[1], ef[2]);
        }
    }

    barrier_lds_only();
    if (nsamp > 0) {
        const int tot = nsamp * 26;
        for (int i = tid; i < tot; i += 512) {
            const int s = i / 26, r = i - s * 26;
            out4[(base + s) * 58 + 32 + r] = obuf[s * ROWA + r];
        }
    }
}

extern "C" void kernel_launch(void* const* d_in, const int* in_sizes, int n_in,
                              void* d_out, int out_size, void* d_ws, size_t ws_size,
                              hipStream_t stream) {
    const float* tau    = (const float*)d_in[0];
    const float* mu     = (const float*)d_in[1];
    const float* mu_bar = (const float*)d_in[2];
    const float* lw     = (const float*)d_in[3];
    const float* h2o    = (const float*)d_in[4];
    const float* o3     = (const float*)d_in[5];
    const float* co2    = (const float*)d_in[6];
    const float* uu     = (const float*)d_in[7];
    const float* n2o    = (const float*)d_in[8];
    const float* ch4    = (const float*)d_in[9];

    const float* Wd0 = (const float*)d_in[10];
    const float* bd0 = (const float*)d_in[11];
    const float* Wf0 = (const float*)d_in[12];
    const float* bf0 = (const float*)d_in[13];
    const float* Wd1 = (const float*)d_in[14];
    const float* bd1 = (const float*)d_in[15];
    const float* Wf1 = (const float*)d_in[16];
    const float* bf1 = (const float*)d_in[17];
    const float* Wd2 = (const float*)d_in[18];
    const float* bd2 = (const float*)d_in[19];
    const float* Wf2 = (const float*)d_in[20];
    const float* bf2 = (const float*)d_in[21];
    const float* Wd3 = (const float*)d_in[22];
    const float* bd3 = (const float*)d_in[23];
    const float* Wf3 = (const float*)d_in[24];
    const float* bf3 = (const float*)d_in[25];

    float* out = (float*)d_out;
    int N = in_sizes[1];  // mu has N elements

    int blocks = (N + SPB - 1) / SPB;
    lps_kernel<<<blocks, 512, 0, stream>>>(
        tau, mu, mu_bar, lw, h2o, o3, co2, uu, n2o, ch4,
        Wd0, bd0, Wf0, bf0, Wd1, bd1, Wf1, bf1,
        Wd2, bd2, Wf2, bf2, Wd3, bd3, Wf3, bf3,
        out, N);
}